// Round 1
// baseline (374.869 us; speedup 1.0000x reference)
//
#include <hip/hip_runtime.h>

// Overlap-add reconstruction (inverse framing), MI355X / gfx950. Round 3.
//
// x: [B=16, FV=2000, FRAME=2048] fp32, HOP=512, PAD0=PAD1=768.
// out[b][o] = (1/cnt) * sum_{f in [max(0,q-3), min(FV-1,q)]} x[b][f][p-512f],
//   p = o + PAD0, q = p>>9. Pure gather: each input element read exactly once
//   (FETCH <= 256 MB), each output written once (WRITE 64 MB) -> BW-bound.
//   Traffic floor 327.7 MB -> ~52 us @ 6.3 TB/s achievable.
//
// R3 changes vs R2 (345.8 us):
//  - Loads are NO LONGER nontemporal. The harness rewrites the input buffer
//    every iteration through the cache hierarchy, so much of the 256 MB input
//    can be resident in the 256 MB Infinity Cache at kernel start; nt loads
//    bypass L3 and forfeit those hits. Regular loads cannot lose for a
//    read-once stream. Stores remain nontemporal (output never re-read here).
//  - ITERS 2 -> 4 (block covers 4096 samples, grid (250,16)): all 16 loads
//    issued before any store (load-all/store-all split), more loads in flight
//    per wave, edge-branch amortized over 2x the work.
//  - Indices into v[][] are compile-time after full unroll (no scratch).

#define FRAME   2048
#define HOP     512
#define NFV     2000
#define PAD0    768
#define OUT_PER_B (NFV * HOP)          // 1,024,000
#define IN_PER_B  (NFV * FRAME)        // 4,096,000
#define BLOCK   256
#define ITERS   4
#define GROUPS_PER_BLOCK (BLOCK * ITERS)            // 1024 groups = 4096 samples
#define GRID_X  (OUT_PER_B / 4 / GROUPS_PER_BLOCK)  // 256000/1024 = 250 exactly

typedef float v4f __attribute__((ext_vector_type(4)));

__global__ __launch_bounds__(BLOCK) void ola_gather_kernel(
    const float* __restrict__ x, float* __restrict__ out)
{
    const int b = blockIdx.y;
    const float* __restrict__ xb = x + (size_t)b * IN_PER_B;
    float* __restrict__ ob = out + (size_t)b * OUT_PER_B;

    const int g0 = blockIdx.x * GROUPS_PER_BLOCK + threadIdx.x;  // float4-group

    // Block's q range is [8*bx+1, 8*bx+9]; interior needs q-3 >= 0 and
    // q <= NFV-1 for all lanes -> bx in [1, GRID_X-2].
    const bool interior = (blockIdx.x >= 1) & (blockIdx.x <= GRID_X - 2);

    if (interior) {
        v4f v[ITERS][4];
#pragma unroll
        for (int it = 0; it < ITERS; ++it) {
            const int o = (g0 + it * BLOCK) * 4;
            const int p = o + PAD0;
            const int q = p >> 9;
            const int r = p & 511;                          // r % 4 == 0
            const float* base = xb + ((size_t)q << 11) + r; // f=q, t=r
            // f = q-j  ->  addr = base - 1536*j floats
            v[it][0] = *(const v4f*)(base);
            v[it][1] = *(const v4f*)(base - 1536);
            v[it][2] = *(const v4f*)(base - 3072);
            v[it][3] = *(const v4f*)(base - 4608);
        }
#pragma unroll
        for (int it = 0; it < ITERS; ++it) {
            const int o = (g0 + it * BLOCK) * 4;
            const v4f s = (v[it][0] + v[it][1] + v[it][2] + v[it][3]) * 0.25f;
            __builtin_nontemporal_store(s, (v4f*)(ob + o));
        }
    } else {
        for (int it = 0; it < ITERS; ++it) {
            const int o = (g0 + it * BLOCK) * 4;
            const int p = o + PAD0;
            const int q = p >> 9;
            v4f acc = {0.f, 0.f, 0.f, 0.f};
            int cnt = 0;
#pragma unroll
            for (int j = 0; j < 4; ++j) {
                const int f = q - j;
                if (f >= 0 && f < NFV) {
                    const int t = p - (f << 9);
                    const v4f v = *(const v4f*)(xb + (size_t)f * FRAME + t);
                    acc += v;
                    ++cnt;
                }
            }
            const float sc = 1.0f / (float)cnt;
            *(v4f*)(ob + o) = acc * sc;
        }
    }
}

extern "C" void kernel_launch(void* const* d_in, const int* in_sizes, int n_in,
                              void* d_out, int out_size, void* d_ws, size_t ws_size,
                              hipStream_t stream)
{
    const float* x = (const float*)d_in[0];
    float* out = (float*)d_out;

    const int B = in_sizes[0] / IN_PER_B;                   // 16
    dim3 grid(GRID_X, B);
    ola_gather_kernel<<<grid, dim3(BLOCK), 0, stream>>>(x, out);
}

// Round 3
// 345.411 us; speedup vs baseline: 1.0853x; 1.0853x over previous
//
#include <hip/hip_runtime.h>

// Overlap-add reconstruction (inverse framing), MI355X / gfx950. Round 5.
// (Identical to Round 4 — that bench died to a container-acquisition infra
//  failure, not a kernel problem. Resubmitting to preserve the single-variable
//  ITERS 2->1 experiment.)
//
// x: [B=16, FV=2000, FRAME=2048] fp32, HOP=512, PAD0=PAD1=768.
// out[b][o] = (1/cnt) * sum_{f in [max(0,q-3), min(FV-1,q)]} x[b][f][p-512f],
//   p = o + PAD0, q = p>>9. Pure gather: each input element read exactly once
//   (FETCH <= 256 MB), each output written once (WRITE 64 MB) -> BW-bound.
//   Traffic floor 327.7 MB -> ~52 us @ 6.3 TB/s achievable.
//
// R4 post-mortem of R3 (374.9 us, +28.3 vs R2's 346.6; dur_us noise is +-1us
// so the regression was real):
//  - R3 changed two things (nt->regular loads, ITERS 2->4 load-all). The
//    1 GB harness fill between restore and kernel flushes L3 entirely, so
//    nt-vs-regular loads is a wash (no residency to exploit either way).
//    The likely culprit is ITERS=4's 16 live v4f (~64 data VGPRs) cutting
//    occupancy from 8 to ~5 waves/SIMD -- TLP loss on a latency-hiding
//    streaming kernel.
// R4/R5 change vs R2 (single variable): ITERS 2 -> 1. Minimal VGPR, max
//    occupancy, 16000 blocks (62.5/CU, tiny tail quantum). nt loads+stores
//    restored (known-best config otherwise).

#define FRAME   2048
#define HOP     512
#define NFV     2000
#define PAD0    768
#define OUT_PER_B (NFV * HOP)          // 1,024,000
#define IN_PER_B  (NFV * FRAME)        // 4,096,000
#define BLOCK   256
#define GRID_X  (OUT_PER_B / 4 / BLOCK)   // 256000/256 = 1000 exactly

typedef float v4f __attribute__((ext_vector_type(4)));

__global__ __launch_bounds__(BLOCK) void ola_gather_kernel(
    const float* __restrict__ x, float* __restrict__ out)
{
    const int b = blockIdx.y;
    const float* __restrict__ xb = x + (size_t)b * IN_PER_B;
    float* __restrict__ ob = out + (size_t)b * OUT_PER_B;

    const int g = blockIdx.x * BLOCK + threadIdx.x;   // float4-group index
    const int o = g * 4;
    const int p = o + PAD0;
    const int q = p >> 9;

    // Block covers o in [1024*bx, 1024*bx+1023], q in [2bx+1, 2bx+3].
    // Interior needs q-3 >= 0 (bx >= 1) and q <= NFV-1 (bx <= GRID_X-2).
    const bool interior = (blockIdx.x >= 1) & (blockIdx.x <= GRID_X - 2);

    if (interior) {
        const int r = p & 511;                          // r % 4 == 0
        const float* base = xb + ((size_t)q << 11) + r; // f=q, t=r
        // f = q-j  ->  addr = base - 1536*j floats
        v4f v0 = __builtin_nontemporal_load((const v4f*)(base));
        v4f v1 = __builtin_nontemporal_load((const v4f*)(base - 1536));
        v4f v2 = __builtin_nontemporal_load((const v4f*)(base - 3072));
        v4f v3 = __builtin_nontemporal_load((const v4f*)(base - 4608));
        v4f s = (v0 + v1 + v2 + v3) * 0.25f;
        __builtin_nontemporal_store(s, (v4f*)(ob + o));
    } else {
        v4f acc = {0.f, 0.f, 0.f, 0.f};
        int cnt = 0;
#pragma unroll
        for (int j = 0; j < 4; ++j) {
            const int f = q - j;
            if (f >= 0 && f < NFV) {
                const int t = p - (f << 9);
                const v4f v = *(const v4f*)(xb + (size_t)f * FRAME + t);
                acc += v;
                ++cnt;
            }
        }
        const float sc = 1.0f / (float)cnt;
        *(v4f*)(ob + o) = acc * sc;
    }
}

extern "C" void kernel_launch(void* const* d_in, const int* in_sizes, int n_in,
                              void* d_out, int out_size, void* d_ws, size_t ws_size,
                              hipStream_t stream)
{
    const float* x = (const float*)d_in[0];
    float* out = (float*)d_out;

    const int B = in_sizes[0] / IN_PER_B;                   // 16
    dim3 grid(GRID_X, B);
    ola_gather_kernel<<<grid, dim3(BLOCK), 0, stream>>>(x, out);
}